// Round 1
// baseline (521.024 us; speedup 1.0000x reference)
//
#include <hip/hip_runtime.h>
#include <math.h>

#define NEGINF (-INFINITY)

// Butterfly argmax across the 64-lane wave over (v, idx).
// Tie-break: lower idx wins (matches jnp.argmax first-occurrence on flat index).
__device__ __forceinline__ void wave_argmax(float& v, int& idx) {
#pragma unroll
    for (int off = 32; off > 0; off >>= 1) {
        float ov = __shfl_xor(v, off, 64);
        int   oi = __shfl_xor(idx, off, 64);
        if (ov > v || (ov == v && oi < idx)) { v = ov; idx = oi; }
    }
}

// One wave (64 lanes) per batch. Lane l owns rows {j*64+l : j=0..3} (max+argcol
// in registers) and the column-mask bits for cols 4l..4l+3 (for cooperative rescan).
__global__ __launch_bounds__(64) void greedy_perm_kernel(
        const float* __restrict__ soft, float* __restrict__ out) {
    const int b = blockIdx.x;
    const int lane = threadIdx.x;
    const size_t base = (size_t)b << 16;          // b * 256 * 256
    const float* sc = soft + base;
    float* ob = out + base;

    float v[4];   // cached row max (NEGINF once row assigned)
    int   c[4];   // cached argmax column (300 = sentinel for assigned)

    // ---- initial per-row scans (private, pipelined float4 loads) ----
#pragma unroll
    for (int j = 0; j < 4; ++j) {
        const int row = j * 64 + lane;
        const float4* rp = (const float4*)(sc + row * 256);
        float bv = NEGINF; int bc = 0;
        for (int k = 0; k < 64; ++k) {
            float4 w = rp[k];
            if (w.x > bv) { bv = w.x; bc = 4 * k + 0; }
            if (w.y > bv) { bv = w.y; bc = 4 * k + 1; }
            if (w.z > bv) { bv = w.z; bc = 4 * k + 2; }
            if (w.w > bv) { bv = w.w; bc = 4 * k + 3; }
        }
        v[j] = bv; c[j] = bc;
    }

    unsigned int colmask = 0;   // 4 bits: cols 4*lane .. 4*lane+3 assigned?

    // ---- 256 sequential greedy steps ----
    for (int step = 0; step < 256; ++step) {
        // local argmax over the 4 owned rows (flat = row*256 + col)
        float bv = v[0];
        int   bf = (lane << 8) | (c[0] & 255);
#pragma unroll
        for (int j = 1; j < 4; ++j) {
            int f = ((j * 64 + lane) << 8) | (c[j] & 255);
            if (v[j] > bv || (v[j] == bv && f < bf)) { bv = v[j]; bf = f; }
        }
        wave_argmax(bv, bf);                 // all lanes converge to (bv, bf)
        const int r  = bf >> 8;
        const int cc = bf & 255;

        if (lane == 0) ob[bf] = 1.0f;        // hard[r][cc] = 1
        if (lane == (r & 63)) { v[r >> 6] = NEGINF; c[r >> 6] = 300; }
        if (lane == (cc >> 2)) colmask |= 1u << (cc & 3);

        // rows whose cached argmax column just got taken -> cooperative rescan
#pragma unroll
        for (int j = 0; j < 4; ++j) {
            unsigned long long m = __ballot(c[j] == cc);
            while (m) {
                const int ln = __builtin_ctzll(m); m &= m - 1;
                const int row = j * 64 + ln;
                // coalesced: 64 lanes x float4 = the whole 256-float row
                float4 w = *(const float4*)(sc + row * 256 + lane * 4);
                float m0 = (colmask & 1u) ? NEGINF : w.x;
                float m1 = (colmask & 2u) ? NEGINF : w.y;
                float m2 = (colmask & 4u) ? NEGINF : w.z;
                float m3 = (colmask & 8u) ? NEGINF : w.w;
                float rv = m0; int rf = 4 * lane + 0;
                if (m1 > rv) { rv = m1; rf = 4 * lane + 1; }
                if (m2 > rv) { rv = m2; rf = 4 * lane + 2; }
                if (m3 > rv) { rv = m3; rf = 4 * lane + 3; }
                wave_argmax(rv, rf);         // tie-break lower col
                if (lane == ln) { v[j] = rv; c[j] = rf; }
            }
        }
    }
}

extern "C" void kernel_launch(void* const* d_in, const int* in_sizes, int n_in,
                              void* d_out, int out_size, void* d_ws, size_t ws_size,
                              hipStream_t stream) {
    const float* soft = (const float*)d_in[0];
    float* out = (float*)d_out;
    const int n_batches = in_sizes[0] >> 16;   // elements / (256*256)

    // d_out is re-poisoned before every timed launch -> must zero it each call.
    hipMemsetAsync(d_out, 0, (size_t)out_size * sizeof(float), stream);
    greedy_perm_kernel<<<n_batches, 64, 0, stream>>>(soft, out);
}

// Round 2
// 327.708 us; speedup vs baseline: 1.5899x; 1.5899x over previous
//
#include <hip/hip_runtime.h>
#include <math.h>

#define NEGINF (-INFINITY)

// One DPP max stage: x = max(x, lanes-moved(x)). bound_ctrl=false + old=x makes
// invalid source lanes contribute x itself (identity for max).
template <int CTRL>
__device__ __forceinline__ float dppmax(float x) {
    int xi = __float_as_int(x);
    int yi = __builtin_amdgcn_update_dpp(xi, xi, CTRL, 0xf, 0xf, false);
    return fmaxf(x, __int_as_float(yi));
}

// Wave64 max via DPP (VALU latency, no LDS): row_shr 1/2/4/8 then row_bcast 15/31.
// Result lands in lane 63; broadcast via readlane.
__device__ __forceinline__ float wave_max64(float x) {
    x = dppmax<0x111>(x);   // row_shr:1
    x = dppmax<0x112>(x);   // row_shr:2
    x = dppmax<0x114>(x);   // row_shr:4
    x = dppmax<0x118>(x);   // row_shr:8
    x = dppmax<0x142>(x);   // row_bcast:15
    x = dppmax<0x143>(x);   // row_bcast:31
    return __int_as_float(__builtin_amdgcn_readlane(__float_as_int(x), 63));
}

// Wave argmax over (v, idx), tie-break lowest idx (matches jnp.argmax first-occurrence).
// Fast path: single lane holds the max -> one dynamic readlane. Tie path is rare.
__device__ __forceinline__ void wave_argmax(float v, int idx, float& out_v, int& out_idx) {
    float mv = wave_max64(v);
    unsigned long long mask = __ballot(v == mv);
    int ln = (int)__builtin_ctzll(mask);
    int bi = __builtin_amdgcn_readlane(idx, ln);
    unsigned long long rest = mask & (mask - 1);
    if (rest) {                       // wave-uniform, almost never taken
        while (rest) {
            int l2 = (int)__builtin_ctzll(rest); rest &= rest - 1;
            int b2 = __builtin_amdgcn_readlane(idx, l2);
            if (b2 < bi) bi = b2;
        }
    }
    out_v = mv; out_idx = bi;
}

// One wave (64 lanes) per batch. Lane l owns rows {j*64+l : j=0..3} (cached
// max+argcol in registers) and column-mask bits for cols 4l..4l+3.
__global__ __launch_bounds__(64, 1) void greedy_perm_kernel(
        const float* __restrict__ soft, float* __restrict__ out) {
    const int b = blockIdx.x;
    const int lane = threadIdx.x;
    const size_t base = (size_t)b << 16;          // b * 256 * 256
    const float* sc = soft + base;
    float* ob = out + base;

    float v[4];   // cached row max (NEGINF once row assigned)
    int   c[4];   // cached argmax column (300 = sentinel for assigned)

#pragma unroll
    for (int j = 0; j < 4; ++j) { v[j] = NEGINF; c[j] = 0; }

    const float4 zero4 = make_float4(0.f, 0.f, 0.f, 0.f);

    // ---- initial per-row scans, 16 loads in flight, fused zero-fill of out ----
    for (int k = 0; k < 64; k += 4) {
        float4 w[4][4];
#pragma unroll
        for (int j = 0; j < 4; ++j) {
            const float4* rp = (const float4*)(sc + (size_t)(j * 64 + lane) * 256);
#pragma unroll
            for (int kk = 0; kk < 4; ++kk) w[j][kk] = rp[k + kk];
        }
#pragma unroll
        for (int j = 0; j < 4; ++j) {
            float4* op = (float4*)(ob + (size_t)(j * 64 + lane) * 256);
#pragma unroll
            for (int kk = 0; kk < 4; ++kk) op[k + kk] = zero4;
        }
#pragma unroll
        for (int j = 0; j < 4; ++j) {
#pragma unroll
            for (int kk = 0; kk < 4; ++kk) {
                const float4 ww = w[j][kk];
                const int bc = 4 * (k + kk);
                if (ww.x > v[j]) { v[j] = ww.x; c[j] = bc + 0; }
                if (ww.y > v[j]) { v[j] = ww.y; c[j] = bc + 1; }
                if (ww.z > v[j]) { v[j] = ww.z; c[j] = bc + 2; }
                if (ww.w > v[j]) { v[j] = ww.w; c[j] = bc + 3; }
            }
        }
    }

    // Drain zero-stores before any 1.0 store can target the same address.
    __threadfence_block();

    unsigned int colmask = 0;   // 4 bits: cols 4*lane .. 4*lane+3 assigned?

    // ---- 256 sequential greedy steps ----
    for (int step = 0; step < 256; ++step) {
        // local argmax over the 4 owned rows (flat = row*256 + col)
        float bv = v[0];
        int   bf = (lane << 8) | (c[0] & 255);
#pragma unroll
        for (int j = 1; j < 4; ++j) {
            int f = ((j * 64 + lane) << 8) | (c[j] & 255);
            if (v[j] > bv || (v[j] == bv && f < bf)) { bv = v[j]; bf = f; }
        }
        float gv; int gf;
        wave_argmax(bv, bf, gv, gf);
        const int r  = gf >> 8;
        const int cc = gf & 255;

        if (lane == 0) ob[gf] = 1.0f;        // hard[r][cc] = 1
        if (lane == (r & 63)) { v[r >> 6] = NEGINF; c[r >> 6] = 300; }
        if (lane == (cc >> 2)) colmask |= 1u << (cc & 3);

        // rows whose cached argmax column just got taken -> cooperative rescan
#pragma unroll
        for (int j = 0; j < 4; ++j) {
            unsigned long long m = __ballot(c[j] == cc);
            while (m) {
                const int ln = (int)__builtin_ctzll(m); m &= m - 1;
                const int row = j * 64 + ln;
                // coalesced: 64 lanes x float4 = the whole 256-float row
                float4 w = *(const float4*)(sc + (size_t)row * 256 + lane * 4);
                float m0 = (colmask & 1u) ? NEGINF : w.x;
                float m1 = (colmask & 2u) ? NEGINF : w.y;
                float m2 = (colmask & 4u) ? NEGINF : w.z;
                float m3 = (colmask & 8u) ? NEGINF : w.w;
                float lv = m0; int lf = 4 * lane + 0;
                if (m1 > lv) { lv = m1; lf = 4 * lane + 1; }
                if (m2 > lv) { lv = m2; lf = 4 * lane + 2; }
                if (m3 > lv) { lv = m3; lf = 4 * lane + 3; }
                float rv; int rf;
                wave_argmax(lv, lf, rv, rf);   // tie-break lower col
                if (lane == ln) { v[j] = rv; c[j] = rf; }
            }
        }
    }
}

extern "C" void kernel_launch(void* const* d_in, const int* in_sizes, int n_in,
                              void* d_out, int out_size, void* d_ws, size_t ws_size,
                              hipStream_t stream) {
    const float* soft = (const float*)d_in[0];
    float* out = (float*)d_out;
    const int n_batches = in_sizes[0] >> 16;   // elements / (256*256)

    // Output zero-fill is fused into the kernel (each block covers its slice).
    greedy_perm_kernel<<<n_batches, 64, 0, stream>>>(soft, out);
}